// Round 3
// baseline (705.358 us; speedup 1.0000x reference)
//
#include <hip/hip_runtime.h>
#include <hip/hip_bf16.h>

// B=32, S=256, E=32, D=32. ALL DEVICE BUFFERS FP32 (reference dtypes).
// x = seq.reshape(32, 8192); Q/K/V = x @ W^T + b   (W: [8192,8192] row-major)
// attn = exp(QK^T)/(rowsum+1e-5) [no max-sub]; out = (attn @ V)/sqrt(32)
//
// ROUND 3: round-2 counters (MfmaUtil 7 / VALUBusy 10 / occ 33, BW 1.9 TB/s
// = 57% of streaming ceiling) => single-buffer 2-barrier stage/compute
// serialization leaves memory idle during compute. Fix = T3 minimum 2-phase:
// double-buffered LDS (2 x 16 KB, BK=64), STAGE(next) issued BEFORE
// compute(cur), ONE __syncthreads per stage (its implicit vmcnt(0) drain sits
// AFTER compute, so next-tile loads are in flight the whole compute phase).
// 3 blocks/CU preserved (96 KB LDS/CU). Swizzle (rule 21): linear GLL dest +
// XOR-preswizzled global source + XOR-swizzled ds_read_b128.
// Accuracy: bf16 hi/lo 3-term scheme unchanged.

#define FIN  8192
#define FOUT 8192
#define SD   8192
#define KSPLIT 2
#define KCHUNK 4096   // FIN / KSPLIT
#define BK 64         // floats staged per row per stage (256 B rows)
#define NT 64         // W rows per block tile
#define NSTG (KCHUNK / BK)   // 64 stages

typedef __attribute__((ext_vector_type(8))) short bf16x8;   // 8 bf16 (4 VGPRs)
typedef __attribute__((ext_vector_type(4))) float f32x4;

static __device__ __forceinline__ short bf16_hi(float w, float& hf) {
    __hip_bfloat16 h = __float2bfloat16(w);      // RNE
    hf = __bfloat162float(h);
    return *(short*)&h;
}
static __device__ __forceinline__ short bf16_of(float w) {
    __hip_bfloat16 h = __float2bfloat16(w);
    return *(short*)&h;
}

static __device__ __forceinline__ void gload_lds16(const float* g, float* l) {
    __builtin_amdgcn_global_load_lds(
        (const __attribute__((address_space(1))) float*)g,
        (__attribute__((address_space(3))) float*)l, 16, 0, 0);
}

// ---------------------------------------------------------------------------
// Kernel 0: split fp32 x -> bf16 hi/lo, written PRE-SWIZZLED in MFMA fragment
// order: buffer[rb][i_step][lane][8] with lane=(quad<<4)|r16 holding
// x[rb*16+r16][i*32+quad*8 .. +8]. GEMM A-load = 1KB wave-contiguous.
// Also bias-primes Q/K/V (65536 float4 each) for split-K atomic combine.
// ---------------------------------------------------------------------------
__global__ __launch_bounds__(256) void split_x_init(
    const float* __restrict__ x,
    short* __restrict__ xh0, short* __restrict__ xh1,
    short* __restrict__ xl0, short* __restrict__ xl1,
    const float* __restrict__ bq, const float* __restrict__ bk,
    const float* __restrict__ bv,
    float* __restrict__ Qf, float* __restrict__ Kf, float* __restrict__ Vf)
{
    const int u = blockIdx.x * 256 + threadIdx.x;      // 0..65535
    if (u < 32768) {
        const int r16 = u & 15;
        const int q   = (u >> 4) & 3;
        const int rb  = (u >> 6) & 1;
        const int i   = u >> 7;                        // k-step 0..255
        const int row = rb * 16 + r16;                 // x row 0..31
        const float4* src = (const float4*)(x + (size_t)row * FIN) + (i * 8 + q * 2);
        float4 a  = src[0];
        float4 b2 = src[1];
        float wf[8] = {a.x, a.y, a.z, a.w, b2.x, b2.y, b2.z, b2.w};
        short hb[8], lb[8];
        #pragma unroll
        for (int j = 0; j < 8; ++j) {
            float hf;
            hb[j] = bf16_hi(wf[j], hf);
            lb[j] = bf16_of(wf[j] - hf);               // exact residual
        }
        bf16x8 vh = {hb[0],hb[1],hb[2],hb[3],hb[4],hb[5],hb[6],hb[7]};
        bf16x8 vl = {lb[0],lb[1],lb[2],lb[3],lb[4],lb[5],lb[6],lb[7]};
        short* dh = rb ? xh1 : xh0;
        short* dl = rb ? xl1 : xl0;
        const int ci = i * 64 + (u & 63);              // (u&63) == quad*16+r16
        ((bf16x8*)dh)[ci] = vh;
        ((bf16x8*)dl)[ci] = vl;
    }
    // bias prime: u covers [32][2048] float4 per matrix
    const int col4 = u & 2047;
    ((float4*)Qf)[u] = ((const float4*)bq)[col4];
    ((float4*)Kf)[u] = ((const float4*)bk)[col4];
    ((float4*)Vf)[u] = ((const float4*)bv)[col4];
}

// ---------------------------------------------------------------------------
// Kernel 1: fused QKV GEMM, double-buffered LDS staging, split-K x2.
// Grid: 3 mats x 128 n-tiles(64 rows) x 2 k-chunks = 768 blocks x 256 thr
//     = exactly 3 blocks/CU (12 waves/CU), LDS 32 KB/block (96 KB/CU).
// Stage = [64 rows][64 floats] (16 KB) via 4 GLL/wave (4 rows x 256 B each).
// Pipeline: STAGE(next) -> COMPUTE(cur) -> barrier (drains next's loads
// AFTER compute) -> swap. Memory pipe never idles.
// ---------------------------------------------------------------------------
__global__ __launch_bounds__(256) void qkv_gemm(
    const short* __restrict__ xh0, const short* __restrict__ xh1,
    const short* __restrict__ xl0, const short* __restrict__ xl1,
    const float* __restrict__ Wq, const float* __restrict__ Wk,
    const float* __restrict__ Wv,
    float* __restrict__ outQ, float* __restrict__ outK, float* __restrict__ outV)
{
    __shared__ float Ws[2][NT * BK];       // 2 x 16 KB

    const int tid  = threadIdx.x;
    const int wave = tid >> 6;
    const int lane = tid & 63;
    const int quad = lane >> 4;
    const int r16  = lane & 15;

    const int bid   = blockIdx.x;          // 0..767
    const int which = bid >> 8;            // 0=Q 1=K 2=V
    const int rem   = bid & 255;
    const int kc    = rem >> 7;            // 0..1 k-chunk
    const int nt    = rem & 127;           // 0..127 n-tile (64 rows)

    const float* W; float* out;
    if (which == 0)      { W = Wq; out = outQ; }
    else if (which == 1) { W = Wk; out = outK; }
    else                 { W = Wv; out = outV; }

    // A fragment bases (pre-swizzled, wave-contiguous 1KB per load)
    const bf16x8* Xh0 = (const bf16x8*)xh0 + lane;
    const bf16x8* Xh1 = (const bf16x8*)xh1 + lane;
    const bf16x8* Xl0 = (const bf16x8*)xl0 + lane;
    const bf16x8* Xl1 = (const bf16x8*)xl1 + lane;

    // Staging geometry: wave stages rows [wave*16, wave*16+16) of the tile.
    // GLL j: rows j*4 + (lane>>4), col byte (r16*16) ^ ((row&7)<<4) so that
    // linear LDS placement == XOR-swizzled layout ((wave*16)&7 == 0, so the
    // in-panel row parity matches the read-side r16&7).
    const size_t wrow_base = (size_t)(nt * 64 + wave * 16) * FIN + (size_t)kc * KCHUNK;
    const int   ldsrow = wave * 16 + r16;
    const int   swz    = (r16 & 7) << 4;

    f32x4 acc0 = {0.f, 0.f, 0.f, 0.f};
    f32x4 acc1 = {0.f, 0.f, 0.f, 0.f};

    auto STAGE = [&](float* buf, int kb) {
        #pragma unroll
        for (int j = 0; j < 4; ++j) {
            const int row   = j * 4 + quad;                       // 0..15 in panel
            const int sbyte = (r16 * 16) ^ ((row & 7) << 4);
            const float* src = W + wrow_base + (size_t)row * FIN + kb * BK + (sbyte >> 2);
            float* dst = buf + (wave * 16 + j * 4) * BK;          // wave-uniform
            gload_lds16(src, dst);
        }
    };

    auto COMPUTE = [&](const float* buf, int kb) {
        const char* WsB = (const char*)buf + ldsrow * (BK * 4);   // 256 B rows
        #pragma unroll
        for (int il = 0; il < 2; ++il) {
            const int i_g = kc * 128 + kb * 2 + il;               // global k-step
            bf16x8 ah0 = Xh0[i_g * 64];
            bf16x8 ah1 = Xh1[i_g * 64];
            bf16x8 al0 = Xl0[i_g * 64];
            bf16x8 al1 = Xl1[i_g * 64];

            const int koff = il * 128 + quad * 32;
            f32x4 w0 = *(const f32x4*)(WsB + ((koff     ) ^ swz));
            f32x4 w1 = *(const f32x4*)(WsB + ((koff + 16) ^ swz));

            float wf[8] = {w0[0], w0[1], w0[2], w0[3], w1[0], w1[1], w1[2], w1[3]};
            short hb[8], lb[8];
            #pragma unroll
            for (int j = 0; j < 8; ++j) {
                float hf;
                hb[j] = bf16_hi(wf[j], hf);
                lb[j] = bf16_of(wf[j] - hf);
            }
            bf16x8 wh = {hb[0],hb[1],hb[2],hb[3],hb[4],hb[5],hb[6],hb[7]};
            bf16x8 wl = {lb[0],lb[1],lb[2],lb[3],lb[4],lb[5],lb[6],lb[7]};

            acc0 = __builtin_amdgcn_mfma_f32_16x16x32_bf16(ah0, wh, acc0, 0, 0, 0);
            acc0 = __builtin_amdgcn_mfma_f32_16x16x32_bf16(al0, wh, acc0, 0, 0, 0);
            acc0 = __builtin_amdgcn_mfma_f32_16x16x32_bf16(ah0, wl, acc0, 0, 0, 0);
            acc1 = __builtin_amdgcn_mfma_f32_16x16x32_bf16(ah1, wh, acc1, 0, 0, 0);
            acc1 = __builtin_amdgcn_mfma_f32_16x16x32_bf16(al1, wh, acc1, 0, 0, 0);
            acc1 = __builtin_amdgcn_mfma_f32_16x16x32_bf16(ah1, wl, acc1, 0, 0, 0);
        }
    };

    float* cur = Ws[0];
    float* nxt = Ws[1];

    STAGE(cur, 0);
    __syncthreads();                       // prologue: one-time full drain

    #pragma unroll 1
    for (int kb = 0; kb < NSTG - 1; ++kb) {
        STAGE(nxt, kb + 1);                // issue next tile's loads FIRST
        COMPUTE(cur, kb);                  // compute while they fly
        __syncthreads();                   // implicit vmcnt(0): next tile ready,
                                           // all waves done reading cur
        float* t = cur; cur = nxt; nxt = t;
    }
    COMPUTE(cur, NSTG - 1);                // epilogue (no prefetch)

    // C/D layout (m89): col = lane&15, row = quad*4 + reg.
    // Output column n; atomicAdd into bias-primed out (split-K combine).
    const int n = nt * 64 + wave * 16 + r16;
    #pragma unroll
    for (int i = 0; i < 4; ++i) {
        const int m = quad * 4 + i;
        atomicAdd(&out[(size_t)m        * FOUT + n], acc0[i]);
        atomicAdd(&out[(size_t)(m + 16) * FOUT + n], acc1[i]);
    }
}

// ---------------------------------------------------------------------------
// Kernel 2: attention, fp32, single pass (no max subtraction — faithful).
// grid = 32 batches x 8 row-tiles(32) = 256 blocks, 512 thr (16 t-chunks).
// Partial buffers padded (stride 33/17) to kill 64-way LDS bank conflicts.
// ---------------------------------------------------------------------------
#define PZS 33
#define PDS 17
__global__ __launch_bounds__(512) void attention(
    const float* __restrict__ Qf, const float* __restrict__ Kf,
    const float* __restrict__ Vf, float* __restrict__ out)
{
    __shared__ float smem[16896 + 544];     // max(K|V 16384, pz 16896) + pden
    float* Ks = smem;
    float* Vs = smem + SD;

    const int b     = blockIdx.x >> 3;
    const int stile = blockIdx.x & 7;
    const int tid   = threadIdx.x;

    const float* Kb = Kf + (size_t)b * SD;
    const float* Vb = Vf + (size_t)b * SD;
    for (int i = tid; i < SD / 4; i += 512) {        // 4 iters each
        ((float4*)Ks)[i] = ((const float4*)Kb)[i];
        ((float4*)Vs)[i] = ((const float4*)Vb)[i];
    }
    __syncthreads();

    const int srow  = tid & 31;
    const int chunk = tid >> 5;             // 0..15, each covers 16 t's
    const int s     = stile * 32 + srow;

    float q[32];
    const float* Qrow = Qf + (size_t)b * SD + (size_t)s * 32;
    #pragma unroll
    for (int d = 0; d < 32; ++d) q[d] = Qrow[d];

    float z[32];
    #pragma unroll
    for (int d = 0; d < 32; ++d) z[d] = 0.f;
    float den = 0.f;

    const int t0 = chunk * 16;
    for (int t = t0; t < t0 + 16; ++t) {
        const float* krow = Ks + t * 32;
        float scr = 0.f;
        #pragma unroll
        for (int d = 0; d < 32; ++d) scr += q[d] * krow[d];
        const float e = __expf(scr);
        den += e;
        const float* vrow = Vs + t * 32;
        #pragma unroll
        for (int d = 0; d < 32; ++d) z[d] += e * vrow[d];
    }

    __syncthreads();                        // done reading Ks/Vs
    float* pz   = smem;                     // [32*16][33]
    float* pden = smem + 16896;             // [32][17]
    #pragma unroll
    for (int d = 0; d < 32; ++d) pz[(srow * 16 + chunk) * PZS + d] = z[d];
    pden[srow * PDS + chunk] = den;
    __syncthreads();

    const int row = tid >> 4;               // 0..31
    const int dq  = tid & 15;               // 0..15 -> 2 output floats
    float dsum = 0.f;
    #pragma unroll
    for (int c = 0; c < 16; ++c) dsum += pden[row * PDS + c];
    const float inv = 0.17677669529663687f / (dsum + 1e-5f);  // (1/sqrt(32))/(den+eps)

    const int so = stile * 32 + row;
    float* orow = out + (size_t)b * SD + (size_t)so * 32 + dq * 2;
    #pragma unroll
    for (int j = 0; j < 2; ++j) {
        float zz = 0.f;
        #pragma unroll
        for (int c = 0; c < 16; ++c) zz += pz[(row * 16 + c) * PZS + dq * 2 + j];
        orow[j] = zz * inv;
    }
}

// ---------------------------------------------------------------------------
extern "C" void kernel_launch(void* const* d_in, const int* in_sizes, int n_in,
                              void* d_out, int out_size, void* d_ws, size_t ws_size,
                              hipStream_t stream)
{
    const float* x  = (const float*)d_in[0];
    const float* Wq = (const float*)d_in[1];
    const float* bq = (const float*)d_in[2];
    const float* Wk = (const float*)d_in[3];
    const float* bk = (const float*)d_in[4];
    const float* Wv = (const float*)d_in[5];
    const float* bv = (const float*)d_in[6];
    float* out = (float*)d_out;

    // ws: xh0|xh1|xl0|xl1 (4 x 256KB fragment-order) | Qf | Kf | Vf  = 4 MB
    short* xh0 = (short*)d_ws;
    short* xh1 = xh0 + 131072;
    short* xl0 = xh1 + 131072;
    short* xl1 = xl0 + 131072;
    float* Qf = (float*)((char*)d_ws + (1u << 20));
    float* Kf = Qf + 262144;
    float* Vf = Kf + 262144;

    split_x_init<<<256, 256, 0, stream>>>(x, xh0, xh1, xl0, xl1,
                                          bq, bk, bv, Qf, Kf, Vf);
    qkv_gemm    <<<768, 256, 0, stream>>>(xh0, xh1, xl0, xl1,
                                          Wq, Wk, Wv, Qf, Kf, Vf);
    attention   <<<256, 512, 0, stream>>>(Qf, Kf, Vf, out);
}

// Round 4
// 692.055 us; speedup vs baseline: 1.0192x; 1.0192x over previous
//
#include <hip/hip_runtime.h>
#include <hip/hip_bf16.h>

// B=32, S=256, E=32, D=32. ALL DEVICE BUFFERS FP32 (reference dtypes).
// x = seq.reshape(32, 8192); Q/K/V = x @ W^T + b   (W: [8192,8192] row-major)
// attn = exp(QK^T)/(rowsum+1e-5) [no max-sub]; out = (attn @ V)/sqrt(32)
//
// ROUND 4: R3 showed __syncthreads() dbuf is a no-op (full vmcnt(0) drain per
// barrier; 237us >= R2's 220). This round = T3+T4 proper (m201-verified
// pattern): raw s_barrier + counted "s_waitcnt vmcnt(6)" inline asm, 3 LDS
// buffers, stage issued 2 ahead -> loads stay in flight ACROSS barriers.
// A-fragments moved into the same global_load_lds pipeline (COMPUTE has zero
// VMEM ops => vmcnt counting exact; also dedups 4x per-wave A reads).
// Per-block K-phase stagger (accumulation order-free) decorrelates column
// windows across blocks (HBM channel spread).
// Accuracy: bf16 hi/lo 3-term scheme unchanged.

#define FIN  8192
#define FOUT 8192
#define SD   8192
#define KSPLIT 4
#define KCHUNK 2048            // FIN / KSPLIT
#define BK 64                  // floats staged per W row per stage (256 B)
#define NT 64                  // W rows per block tile
#define NSTG (KCHUNK / BK)     // 32 stages per block
#define BUFF (NT * BK + 2048)  // floats: W 4096 + A 8KB(=2048 float-equiv)

typedef __attribute__((ext_vector_type(8))) short bf16x8;   // 8 bf16 (4 VGPRs)
typedef __attribute__((ext_vector_type(4))) float f32x4;
typedef __attribute__((ext_vector_type(4))) short short4v;

static __device__ __forceinline__ short bf16_hi(float w, float& hf) {
    __hip_bfloat16 h = __float2bfloat16(w);      // RNE
    hf = __bfloat162float(h);
    return *(short*)&h;
}
static __device__ __forceinline__ short bf16_of(float w) {
    __hip_bfloat16 h = __float2bfloat16(w);
    return *(short*)&h;
}

static __device__ __forceinline__ void gload_lds16(const float* g, float* l) {
    __builtin_amdgcn_global_load_lds(
        (const __attribute__((address_space(1))) float*)g,
        (__attribute__((address_space(3))) float*)l, 16, 0, 0);
}

// ---------------------------------------------------------------------------
// Kernel 0: split fp32 x -> bf16 hi/lo, written PRE-SWIZZLED in MFMA fragment
// order: buffer[rb][i_step][lane][8] with lane=(quad<<4)|r16 holding
// x[rb*16+r16][i*32+quad*8 .. +8].  Also bias-primes Q/K/V for the split-K
// atomic combine.
// ---------------------------------------------------------------------------
__global__ __launch_bounds__(256) void split_x_init(
    const float* __restrict__ x,
    short* __restrict__ xh0, short* __restrict__ xh1,
    short* __restrict__ xl0, short* __restrict__ xl1,
    const float* __restrict__ bq, const float* __restrict__ bk,
    const float* __restrict__ bv,
    float* __restrict__ Qf, float* __restrict__ Kf, float* __restrict__ Vf)
{
    const int u = blockIdx.x * 256 + threadIdx.x;      // 0..65535
    if (u < 32768) {
        const int r16 = u & 15;
        const int q   = (u >> 4) & 3;
        const int rb  = (u >> 6) & 1;
        const int i   = u >> 7;                        // k-step 0..255
        const int row = rb * 16 + r16;                 // x row 0..31
        const float4* src = (const float4*)(x + (size_t)row * FIN) + (i * 8 + q * 2);
        float4 a  = src[0];
        float4 b2 = src[1];
        float wf[8] = {a.x, a.y, a.z, a.w, b2.x, b2.y, b2.z, b2.w};
        short hb[8], lb[8];
        #pragma unroll
        for (int j = 0; j < 8; ++j) {
            float hf;
            hb[j] = bf16_hi(wf[j], hf);
            lb[j] = bf16_of(wf[j] - hf);               // exact residual
        }
        bf16x8 vh = {hb[0],hb[1],hb[2],hb[3],hb[4],hb[5],hb[6],hb[7]};
        bf16x8 vl = {lb[0],lb[1],lb[2],lb[3],lb[4],lb[5],lb[6],lb[7]};
        short* dh = rb ? xh1 : xh0;
        short* dl = rb ? xl1 : xl0;
        const int ci = i * 64 + (u & 63);              // (u&63) == quad*16+r16
        ((bf16x8*)dh)[ci] = vh;
        ((bf16x8*)dl)[ci] = vl;
    }
    // bias prime: u covers [32][2048] float4 per matrix
    const int col4 = u & 2047;
    ((float4*)Qf)[u] = ((const float4*)bq)[col4];
    ((float4*)Kf)[u] = ((const float4*)bk)[col4];
    ((float4*)Vf)[u] = ((const float4*)bv)[col4];
}

// ---------------------------------------------------------------------------
// Kernel 1: fused QKV GEMM, no-drain 3-deep GLL pipeline, split-K x4.
// Grid: 3 mats x 128 n-tiles(64 rows) x 4 k-chunks = 1536 blocks x 256 thr.
// LDS 72 KB/block (3 bufs x [W 16KB + A 8KB]) -> 2 blocks/CU, 8 waves/CU.
// Per stage per wave: 6 GLL (4 W-panel rows x4, 2 A-chunks). Steady state:
// 12 GLL (12 KB) in flight per wave, never drained below 6 in the loop.
// Schedule/iter t: waitcnt vmcnt(6) [stage t landed]; s_barrier; sched_bar;
//                  STAGE(t+2 -> buf[(t+2)%3]); COMPUTE(buf[t%3]).
// Per-block K-phase stagger (phase = bid*13 & 31) spreads column windows.
// ---------------------------------------------------------------------------
__global__ __launch_bounds__(256, 2) void qkv_gemm(
    const short* __restrict__ xh0, const short* __restrict__ xh1,
    const short* __restrict__ xl0, const short* __restrict__ xl1,
    const float* __restrict__ Wq, const float* __restrict__ Wk,
    const float* __restrict__ Wv,
    float* __restrict__ outQ, float* __restrict__ outK, float* __restrict__ outV)
{
    __shared__ float Ws[3 * BUFF];         // 72 KB

    const int tid  = threadIdx.x;
    const int wave = tid >> 6;
    const int lane = tid & 63;
    const int quad = lane >> 4;
    const int r16  = lane & 15;

    const int bid   = blockIdx.x;          // 0..1535
    const int which = bid >> 9;            // 0=Q 1=K 2=V
    const int rem   = bid & 511;
    const int kc    = rem >> 7;            // 0..3 k-chunk
    const int nt    = rem & 127;           // 0..127 n-tile (64 rows)

    const float* W; float* out;
    if (which == 0)      { W = Wq; out = outQ; }
    else if (which == 1) { W = Wk; out = outK; }
    else                 { W = Wv; out = outV; }

    // Wave stages/reads only its own 16-row W panel; A chunks are block-shared.
    const size_t wrow_base = (size_t)(nt * 64 + wave * 16) * FIN + (size_t)kc * KCHUNK;
    const int   ldsrow = wave * 16 + r16;
    const int   swz    = (r16 & 7) << 4;

    f32x4 acc0 = {0.f, 0.f, 0.f, 0.f};
    f32x4 acc1 = {0.f, 0.f, 0.f, 0.f};

    // STAGE(buf, s): 6 GLL/wave. W: rows j*4+quad, col window s*BK, source
    // XOR-preswizzled (linear LDS dest == swizzled layout, rule 21).
    // A: chunk c = wave*2+j; c -> il=c>>2, kind=c&3 (h0,h1,l0,l1); 1KB each,
    // copied verbatim from the fragment-ordered xh/xl buffers.
    auto STAGE = [&](float* buf, int s) {
        #pragma unroll
        for (int j = 0; j < 4; ++j) {
            const int row   = j * 4 + quad;                       // 0..15 in panel
            const int sbyte = (r16 * 16) ^ ((row & 7) << 4);
            const float* src = W + wrow_base + (size_t)row * FIN + s * BK + (sbyte >> 2);
            float* dst = buf + (wave * 16 + j * 4) * BK;          // wave-uniform
            gload_lds16(src, dst);
        }
        short* Abuf = (short*)(buf + NT * BK);
        #pragma unroll
        for (int j = 0; j < 2; ++j) {
            const int c    = wave * 2 + j;                        // 0..7
            const int il   = c >> 2;
            const int kind = c & 3;
            const short* base = (kind == 0) ? xh0 : (kind == 1) ? xh1
                              : (kind == 2) ? xl0 : xl1;
            const int i_g  = kc * (KCHUNK / 32) + s * 2 + il;     // global k-step
            const short* src = base + (size_t)(i_g * 64 + lane) * 8;
            short* dst = Abuf + c * 512;                          // wave-uniform
            gload_lds16((const float*)src, (float*)dst);
        }
    };

    // COMPUTE(buf): pure LDS + VALU + MFMA (zero VMEM => vmcnt stays exact).
    auto COMPUTE = [&](const float* buf) {
        const char*  WsB  = (const char*)buf + ldsrow * (BK * 4); // 256 B rows
        const short* Abuf = (const short*)(buf + NT * BK);
        #pragma unroll
        for (int il = 0; il < 2; ++il) {
            bf16x8 ah0 = *(const bf16x8*)(Abuf + (il * 4 + 0) * 512 + lane * 8);
            bf16x8 ah1 = *(const bf16x8*)(Abuf + (il * 4 + 1) * 512 + lane * 8);
            bf16x8 al0 = *(const bf16x8*)(Abuf + (il * 4 + 2) * 512 + lane * 8);
            bf16x8 al1 = *(const bf16x8*)(Abuf + (il * 4 + 3) * 512 + lane * 8);

            const int koff = il * 128 + quad * 32;
            f32x4 w0 = *(const f32x4*)(WsB + ((koff     ) ^ swz));
            f32x4 w1 = *(const f32x4*)(WsB + ((koff + 16) ^ swz));

            float wf[8] = {w0[0], w0[1], w0[2], w0[3], w1[0], w1[1], w1[2], w1[3]};
            short hb[8], lb[8];
            #pragma unroll
            for (int j = 0; j < 8; ++j) {
                float hf;
                hb[j] = bf16_hi(wf[j], hf);
                lb[j] = bf16_of(wf[j] - hf);
            }
            bf16x8 wh = {hb[0],hb[1],hb[2],hb[3],hb[4],hb[5],hb[6],hb[7]};
            bf16x8 wl = {lb[0],lb[1],lb[2],lb[3],lb[4],lb[5],lb[6],lb[7]};

            acc0 = __builtin_amdgcn_mfma_f32_16x16x32_bf16(ah0, wh, acc0, 0, 0, 0);
            acc0 = __builtin_amdgcn_mfma_f32_16x16x32_bf16(al0, wh, acc0, 0, 0, 0);
            acc0 = __builtin_amdgcn_mfma_f32_16x16x32_bf16(ah0, wl, acc0, 0, 0, 0);
            acc1 = __builtin_amdgcn_mfma_f32_16x16x32_bf16(ah1, wh, acc1, 0, 0, 0);
            acc1 = __builtin_amdgcn_mfma_f32_16x16x32_bf16(al1, wh, acc1, 0, 0, 0);
            acc1 = __builtin_amdgcn_mfma_f32_16x16x32_bf16(ah1, wl, acc1, 0, 0, 0);
        }
    };

    // K-phase stagger: start each block at a different stage (MFMA accumulate
    // is order-independent). Decorrelates column windows across blocks.
    const int phase = (bid * 13) & (NSTG - 1);

    float* b0 = Ws;
    float* b1 = Ws + BUFF;
    float* b2 = Ws + 2 * BUFF;

    STAGE(b0, phase);
    STAGE(b1, (phase + 1) & (NSTG - 1));

    float* bc = b0; float* bn = b1; float* bnn = b2;

    #pragma unroll 1
    for (int t = 0; t < NSTG; ++t) {
        if (t < NSTG - 1) {
            asm volatile("s_waitcnt vmcnt(6)" ::: "memory");  // stage t landed
        } else {
            asm volatile("s_waitcnt vmcnt(0)" ::: "memory");  // last stage
        }
        __builtin_amdgcn_s_barrier();          // raw barrier: NO vmcnt drain
        __builtin_amdgcn_sched_barrier(0);     // fence: no ds_read hoisting
        if (t < NSTG - 2)
            STAGE(bnn, (phase + t + 2) & (NSTG - 1));
        COMPUTE(bc);
        float* tmp = bc; bc = bn; bn = bnn; bnn = tmp;
    }

    // C/D layout (m89): col = lane&15, row = quad*4 + reg.
    // Output column n; atomicAdd into bias-primed out (split-K combine).
    const int n = nt * 64 + wave * 16 + r16;
    #pragma unroll
    for (int i = 0; i < 4; ++i) {
        const int m = quad * 4 + i;
        atomicAdd(&out[(size_t)m        * FOUT + n], acc0[i]);
        atomicAdd(&out[(size_t)(m + 16) * FOUT + n], acc1[i]);
    }
}

// ---------------------------------------------------------------------------
// Kernel 2: attention, fp32, single pass (no max subtraction — faithful).
// grid = 32 batches x 8 row-tiles(32) = 256 blocks, 512 thr (16 t-chunks).
// Partial buffers padded (stride 33/17) to kill 64-way LDS bank conflicts.
// ---------------------------------------------------------------------------
#define PZS 33
#define PDS 17
__global__ __launch_bounds__(512) void attention(
    const float* __restrict__ Qf, const float* __restrict__ Kf,
    const float* __restrict__ Vf, float* __restrict__ out)
{
    __shared__ float smem[16896 + 544];     // max(K|V 16384, pz 16896) + pden
    float* Ks = smem;
    float* Vs = smem + SD;

    const int b     = blockIdx.x >> 3;
    const int stile = blockIdx.x & 7;
    const int tid   = threadIdx.x;

    const float* Kb = Kf + (size_t)b * SD;
    const float* Vb = Vf + (size_t)b * SD;
    for (int i = tid; i < SD / 4; i += 512) {        // 4 iters each
        ((float4*)Ks)[i] = ((const float4*)Kb)[i];
        ((float4*)Vs)[i] = ((const float4*)Vb)[i];
    }
    __syncthreads();

    const int srow  = tid & 31;
    const int chunk = tid >> 5;             // 0..15, each covers 16 t's
    const int s     = stile * 32 + srow;

    float q[32];
    const float* Qrow = Qf + (size_t)b * SD + (size_t)s * 32;
    #pragma unroll
    for (int d = 0; d < 32; ++d) q[d] = Qrow[d];

    float z[32];
    #pragma unroll
    for (int d = 0; d < 32; ++d) z[d] = 0.f;
    float den = 0.f;

    const int t0 = chunk * 16;
    for (int t = t0; t < t0 + 16; ++t) {
        const float* krow = Ks + t * 32;
        float scr = 0.f;
        #pragma unroll
        for (int d = 0; d < 32; ++d) scr += q[d] * krow[d];
        const float e = __expf(scr);
        den += e;
        const float* vrow = Vs + t * 32;
        #pragma unroll
        for (int d = 0; d < 32; ++d) z[d] += e * vrow[d];
    }

    __syncthreads();                        // done reading Ks/Vs
    float* pz   = smem;                     // [32*16][33]
    float* pden = smem + 16896;             // [32][17]
    #pragma unroll
    for (int d = 0; d < 32; ++d) pz[(srow * 16 + chunk) * PZS + d] = z[d];
    pden[srow * PDS + chunk] = den;
    __syncthreads();

    const int row = tid >> 4;               // 0..31
    const int dq  = tid & 15;               // 0..15 -> 2 output floats
    float dsum = 0.f;
    #pragma unroll
    for (int c = 0; c < 16; ++c) dsum += pden[row * PDS + c];
    const float inv = 0.17677669529663687f / (dsum + 1e-5f);  // (1/sqrt(32))/(den+eps)

    const int so = stile * 32 + row;
    float* orow = out + (size_t)b * SD + (size_t)so * 32 + dq * 2;
    #pragma unroll
    for (int j = 0; j < 2; ++j) {
        float zz = 0.f;
        #pragma unroll
        for (int c = 0; c < 16; ++c) zz += pz[(row * 16 + c) * PZS + dq * 2 + j];
        orow[j] = zz * inv;
    }
}

// ---------------------------------------------------------------------------
extern "C" void kernel_launch(void* const* d_in, const int* in_sizes, int n_in,
                              void* d_out, int out_size, void* d_ws, size_t ws_size,
                              hipStream_t stream)
{
    const float* x  = (const float*)d_in[0];
    const float* Wq = (const float*)d_in[1];
    const float* bq = (const float*)d_in[2];
    const float* Wk = (const float*)d_in[3];
    const float* bk = (const float*)d_in[4];
    const float* Wv = (const float*)d_in[5];
    const float* bv = (const float*)d_in[6];
    float* out = (float*)d_out;

    // ws: xh0|xh1|xl0|xl1 (4 x 256KB fragment-order) | Qf | Kf | Vf  = 4 MB
    short* xh0 = (short*)d_ws;
    short* xh1 = xh0 + 131072;
    short* xl0 = xh1 + 131072;
    short* xl1 = xl0 + 131072;
    float* Qf = (float*)((char*)d_ws + (1u << 20));
    float* Kf = Qf + 262144;
    float* Vf = Kf + 262144;

    split_x_init<<<256, 256, 0, stream>>>(x, xh0, xh1, xl0, xl1,
                                          bq, bk, bv, Qf, Kf, Vf);
    qkv_gemm    <<<1536, 256, 0, stream>>>(xh0, xh1, xl0, xl1,
                                           Wq, Wk, Wv, Qf, Kf, Vf);
    attention   <<<256, 512, 0, stream>>>(Qf, Kf, Vf, out);
}